// Round 1
// baseline (1688.433 us; speedup 1.0000x reference)
//
#include <hip/hip_runtime.h>

#define NN 100000   // nodes
#define NE 640000   // edges
#define RR 8        // relations
// D = HID = OUT = 128 hard-coded below.

// ---- workspace layout (bytes) ----
// agg/msg : [0,           51200000)   float  N*128
// mid     : [51200000,    153600000)  float  N*256
// bucket  : [153600000,   156160000)  int    E
// meta    : [156160000,   +128)       int[32]: cnt[0..7], off[8..16], cur[17..24]
// required ws_size >= 156160128 bytes

extern __shared__ float lds[];

// ---------------- bucketing ----------------
__global__ void k_hist(const int* __restrict__ et, int* __restrict__ meta) {
  __shared__ int h[RR];
  const int tid = threadIdx.x;
  if (tid < RR) h[tid] = 0;
  __syncthreads();
  const int e = blockIdx.x * 256 + tid;
  if (e < NE) atomicAdd(&h[et[e]], 1);
  __syncthreads();
  if (tid < RR) atomicAdd(&meta[tid], h[tid]);
}

__global__ void k_scan(int* __restrict__ meta) {
  int s = 0;
  for (int r = 0; r < RR; ++r) { meta[8 + r] = s; meta[17 + r] = s; s += meta[r]; }
  meta[8 + RR] = s;
}

__global__ void k_scatter(const int* __restrict__ et, int* __restrict__ meta,
                          int* __restrict__ bucket) {
  __shared__ int lh[RR], lbase[RR];
  const int tid = threadIdx.x;
  if (tid < RR) lh[tid] = 0;
  __syncthreads();
  const int e = blockIdx.x * 256 + tid;
  int r = 0, lp = 0;
  if (e < NE) { r = et[e]; lp = atomicAdd(&lh[r], 1); }
  __syncthreads();
  if (tid < RR) lbase[tid] = atomicAdd(&meta[17 + tid], lh[tid]);
  __syncthreads();
  if (e < NE) bucket[lbase[r] + lp] = e;
}

// ---------------- edge GEMM + scatter-add ----------------
// one block per 32-edge chunk of the relation-bucketed edge list
__global__ __launch_bounds__(256) void k_edge(
    const float* __restrict__ x, const int* __restrict__ src,
    const int* __restrict__ dst, const float* __restrict__ W_rel,
    const int* __restrict__ meta, const int* __restrict__ bucket,
    float* __restrict__ agg) {
  float* Ws  = lds;         // [64][128]  32KB (K-slice of W_rel[r])
  float* XgT = lds + 8192;  // [128][32]  16KB (gathered x rows, transposed)
  const int tid = threadIdx.x;
  const int tc = tid & 31, tr = tid >> 5;
  const int c0 = 4 * tc, i0 = 4 * tr;
  const int si = tid >> 3, sj = tid & 7;

  int off[RR + 1];
#pragma unroll
  for (int r = 0; r <= RR; ++r) off[r] = meta[8 + r];

  int p = blockIdx.x * 32;
  const int pend = p + 32;   // NE divisible by 32
  while (p < pend) {
    int r = 0;
    while (off[r + 1] <= p) ++r;          // relation of position p
    const int send = (pend < off[r + 1]) ? pend : off[r + 1];
    const int cnt = send - p;             // edges in this uniform-relation segment

    // stage gathered x rows (transposed): 8 threads per row, 16 floats each
    if (si < cnt) {
      const int e = bucket[p + si];
      const float* xr = x + (size_t)src[e] * 128 + sj * 16;
#pragma unroll
      for (int t = 0; t < 16; t += 4) {
        const float4 v = *(const float4*)(xr + t);
        const int k = sj * 16 + t;
        XgT[(k + 0) * 32 + si] = v.x;
        XgT[(k + 1) * 32 + si] = v.y;
        XgT[(k + 2) * 32 + si] = v.z;
        XgT[(k + 3) * 32 + si] = v.w;
      }
    }

    float acc[4][4] = {};
    const float* wbase = W_rel + (size_t)r * 16384;
#pragma unroll
    for (int s = 0; s < 2; ++s) {
      for (int idx = tid * 4; idx < 8192; idx += 1024)
        *(float4*)&Ws[idx] = *(const float4*)&wbase[s * 8192 + idx];
      __syncthreads();
#pragma unroll 4
      for (int kk = 0; kk < 64; ++kk) {
        const float4 av = *(const float4*)&XgT[(s * 64 + kk) * 32 + i0];
        const float4 bv = *(const float4*)&Ws[kk * 128 + c0];
        const float a[4] = {av.x, av.y, av.z, av.w};
        const float b[4] = {bv.x, bv.y, bv.z, bv.w};
#pragma unroll
        for (int ri = 0; ri < 4; ++ri)
#pragma unroll
          for (int ci = 0; ci < 4; ++ci)
            acc[ri][ci] = fmaf(a[ri], b[ci], acc[ri][ci]);
      }
      __syncthreads();
    }

#pragma unroll
    for (int ri = 0; ri < 4; ++ri) {
      const int i = i0 + ri;
      if (i < cnt) {
        const int e = bucket[p + i];
        float* ap = agg + (size_t)dst[e] * 128 + c0;
        atomicAdd(ap + 0, acc[ri][0]);
        atomicAdd(ap + 1, acc[ri][1]);
        atomicAdd(ap + 2, acc[ri][2]);
        atomicAdd(ap + 3, acc[ri][3]);
      }
    }
    p = send;
  }
}

// ---------------- msg = agg + x @ loop_w + rel_bias (in place over agg) ----
__global__ __launch_bounds__(256) void k_msg(
    const float* __restrict__ x, const float* __restrict__ loop_w,
    const float* __restrict__ rel_bias, float* __restrict__ agg) {
  float* Ws  = lds;         // [64][128]
  float* XgT = lds + 8192;  // [128][32]
  const int tid = threadIdx.x;
  const int tc = tid & 31, tr = tid >> 5;
  const int c0 = 4 * tc, i0 = 4 * tr;
  const int si = tid >> 3, sj = tid & 7;
  const int v0 = blockIdx.x * 32;   // NN divisible by 32

  {
    const float* xr = x + (size_t)(v0 + si) * 128 + sj * 16;
#pragma unroll
    for (int t = 0; t < 16; t += 4) {
      const float4 v = *(const float4*)(xr + t);
      const int k = sj * 16 + t;
      XgT[(k + 0) * 32 + si] = v.x;
      XgT[(k + 1) * 32 + si] = v.y;
      XgT[(k + 2) * 32 + si] = v.z;
      XgT[(k + 3) * 32 + si] = v.w;
    }
  }

  float acc[4][4] = {};
#pragma unroll
  for (int s = 0; s < 2; ++s) {
    for (int idx = tid * 4; idx < 8192; idx += 1024)
      *(float4*)&Ws[idx] = *(const float4*)&loop_w[s * 8192 + idx];
    __syncthreads();
#pragma unroll 4
    for (int kk = 0; kk < 64; ++kk) {
      const float4 av = *(const float4*)&XgT[(s * 64 + kk) * 32 + i0];
      const float4 bv = *(const float4*)&Ws[kk * 128 + c0];
      const float a[4] = {av.x, av.y, av.z, av.w};
      const float b[4] = {bv.x, bv.y, bv.z, bv.w};
#pragma unroll
      for (int ri = 0; ri < 4; ++ri)
#pragma unroll
        for (int ci = 0; ci < 4; ++ci)
          acc[ri][ci] = fmaf(a[ri], b[ci], acc[ri][ci]);
    }
    __syncthreads();
  }

  const float4 bb = *(const float4*)&rel_bias[c0];
#pragma unroll
  for (int ri = 0; ri < 4; ++ri) {
    const size_t row = (size_t)(v0 + i0 + ri) * 128 + c0;
    const float4 g = *(const float4*)&agg[row];
    float4 o;
    o.x = acc[ri][0] + g.x + bb.x;
    o.y = acc[ri][1] + g.y + bb.y;
    o.z = acc[ri][2] + g.z + bb.z;
    o.w = acc[ri][3] + g.w + bb.w;
    *(float4*)&agg[row] = o;
  }
}

// ---------------- mid = tanh([x | msg] @ W1 + b1) ----------------
__global__ __launch_bounds__(256) void k_mlp1(
    const float* __restrict__ x, const float* __restrict__ msg,
    const float* __restrict__ W1, const float* __restrict__ b1,
    float* __restrict__ mid) {
  float* Ws  = lds;         // [32][256] 32KB (K-slice of W1)
  float* ATs = lds + 8192;  // [32][32]   4KB (K-slice of A, transposed)
  const int tid = threadIdx.x;
  const int tc = tid & 31, tr = tid >> 5;
  const int c0 = 4 * tc, i0 = 4 * tr;
  const int si = tid >> 3, sj = tid & 7;
  const int v0 = blockIdx.x * 32;

  float acc[4][8] = {};
  for (int s = 0; s < 8; ++s) {
    {  // stage A slice: global k = s*32 + sj*4 .. +3 (slice never straddles x/msg)
      const int kg = s * 32 + sj * 4;
      const float* ap = (kg < 128) ? x + (size_t)(v0 + si) * 128 + kg
                                   : msg + (size_t)(v0 + si) * 128 + (kg - 128);
      const float4 v = *(const float4*)ap;
      ATs[(sj * 4 + 0) * 32 + si] = v.x;
      ATs[(sj * 4 + 1) * 32 + si] = v.y;
      ATs[(sj * 4 + 2) * 32 + si] = v.z;
      ATs[(sj * 4 + 3) * 32 + si] = v.w;
    }
    for (int idx = tid * 4; idx < 8192; idx += 1024)
      *(float4*)&Ws[idx] = *(const float4*)&W1[s * 8192 + idx];
    __syncthreads();
#pragma unroll 4
    for (int kk = 0; kk < 32; ++kk) {
      const float4 av  = *(const float4*)&ATs[kk * 32 + i0];
      const float4 blo = *(const float4*)&Ws[kk * 256 + c0];
      const float4 bhi = *(const float4*)&Ws[kk * 256 + 128 + c0];
      const float a[4]  = {av.x, av.y, av.z, av.w};
      const float bl[4] = {blo.x, blo.y, blo.z, blo.w};
      const float bh[4] = {bhi.x, bhi.y, bhi.z, bhi.w};
#pragma unroll
      for (int ri = 0; ri < 4; ++ri)
#pragma unroll
        for (int ci = 0; ci < 4; ++ci) {
          acc[ri][ci]     = fmaf(a[ri], bl[ci], acc[ri][ci]);
          acc[ri][4 + ci] = fmaf(a[ri], bh[ci], acc[ri][4 + ci]);
        }
    }
    __syncthreads();
  }

  const float4 b1lo = *(const float4*)&b1[c0];
  const float4 b1hi = *(const float4*)&b1[128 + c0];
#pragma unroll
  for (int ri = 0; ri < 4; ++ri) {
    const size_t row = (size_t)(v0 + i0 + ri) * 256;
    float4 o1, o2;
    o1.x = tanhf(acc[ri][0] + b1lo.x);
    o1.y = tanhf(acc[ri][1] + b1lo.y);
    o1.z = tanhf(acc[ri][2] + b1lo.z);
    o1.w = tanhf(acc[ri][3] + b1lo.w);
    o2.x = tanhf(acc[ri][4] + b1hi.x);
    o2.y = tanhf(acc[ri][5] + b1hi.y);
    o2.z = tanhf(acc[ri][6] + b1hi.z);
    o2.w = tanhf(acc[ri][7] + b1hi.w);
    *(float4*)&mid[row + c0] = o1;
    *(float4*)&mid[row + 128 + c0] = o2;
  }
}

// ---------------- out = [x | mid] @ W2 + b2 ----------------
__global__ __launch_bounds__(256) void k_mlp2(
    const float* __restrict__ x, const float* __restrict__ mid,
    const float* __restrict__ W2, const float* __restrict__ b2,
    float* __restrict__ out) {
  float* Ws  = lds;         // [64][128] 32KB (K-slice of W2)
  float* ATs = lds + 8192;  // [64][32]   8KB
  const int tid = threadIdx.x;
  const int tc = tid & 31, tr = tid >> 5;
  const int c0 = 4 * tc, i0 = 4 * tr;
  const int si = tid >> 3, sj = tid & 7;
  const int v0 = blockIdx.x * 32;

  float acc[4][4] = {};
  for (int s = 0; s < 6; ++s) {
    {  // stage A slice: global k = s*64 + sj*8 .. +7
      const int kg = s * 64 + sj * 8;
      const float* ap = (kg < 128) ? x + (size_t)(v0 + si) * 128 + kg
                                   : mid + (size_t)(v0 + si) * 256 + (kg - 128);
#pragma unroll
      for (int t = 0; t < 8; t += 4) {
        const float4 v = *(const float4*)(ap + t);
        const int kl = sj * 8 + t;
        ATs[(kl + 0) * 32 + si] = v.x;
        ATs[(kl + 1) * 32 + si] = v.y;
        ATs[(kl + 2) * 32 + si] = v.z;
        ATs[(kl + 3) * 32 + si] = v.w;
      }
    }
    for (int idx = tid * 4; idx < 8192; idx += 1024)
      *(float4*)&Ws[idx] = *(const float4*)&W2[s * 8192 + idx];
    __syncthreads();
#pragma unroll 4
    for (int kk = 0; kk < 64; ++kk) {
      const float4 av = *(const float4*)&ATs[kk * 32 + i0];
      const float4 bv = *(const float4*)&Ws[kk * 128 + c0];
      const float a[4] = {av.x, av.y, av.z, av.w};
      const float b[4] = {bv.x, bv.y, bv.z, bv.w};
#pragma unroll
      for (int ri = 0; ri < 4; ++ri)
#pragma unroll
        for (int ci = 0; ci < 4; ++ci)
          acc[ri][ci] = fmaf(a[ri], b[ci], acc[ri][ci]);
    }
    __syncthreads();
  }

  const float4 bb = *(const float4*)&b2[c0];
#pragma unroll
  for (int ri = 0; ri < 4; ++ri) {
    const size_t row = (size_t)(v0 + i0 + ri) * 128 + c0;
    float4 o;
    o.x = acc[ri][0] + bb.x;
    o.y = acc[ri][1] + bb.y;
    o.z = acc[ri][2] + bb.z;
    o.w = acc[ri][3] + bb.w;
    *(float4*)&out[row] = o;
  }
}

extern "C" void kernel_launch(void* const* d_in, const int* in_sizes, int n_in,
                              void* d_out, int out_size, void* d_ws, size_t ws_size,
                              hipStream_t stream) {
  (void)in_sizes; (void)n_in; (void)out_size; (void)ws_size;
  const float* x        = (const float*)d_in[0];
  const int*   src      = (const int*)d_in[1];
  const int*   dst      = (const int*)d_in[2];
  const int*   et       = (const int*)d_in[3];
  const float* W_rel    = (const float*)d_in[4];
  const float* loop_w   = (const float*)d_in[5];
  const float* rel_bias = (const float*)d_in[6];
  const float* W1       = (const float*)d_in[7];
  const float* b1       = (const float*)d_in[8];
  const float* W2       = (const float*)d_in[9];
  const float* b2       = (const float*)d_in[10];
  float* out = (float*)d_out;

  char* ws = (char*)d_ws;
  float* agg   = (float*)ws;                    // N*128 floats
  float* mid   = (float*)(ws + 51200000);       // N*256 floats
  int*   bucket = (int*)(ws + 153600000);       // E ints
  int*   meta  = (int*)(ws + 156160000);        // 32 ints

  hipMemsetAsync(agg, 0, (size_t)NN * 128 * sizeof(float), stream);
  hipMemsetAsync(meta, 0, 128, stream);

  k_hist<<<(NE + 255) / 256, 256, 0, stream>>>(et, meta);
  k_scan<<<1, 1, 0, stream>>>(meta);
  k_scatter<<<(NE + 255) / 256, 256, 0, stream>>>(et, meta, bucket);
  k_edge<<<NE / 32, 256, 49152, stream>>>(x, src, dst, W_rel, meta, bucket, agg);
  k_msg<<<NN / 32, 256, 49152, stream>>>(x, loop_w, rel_bias, agg);
  k_mlp1<<<NN / 32, 256, 36864, stream>>>(x, agg, W1, b1, mid);
  k_mlp2<<<NN / 32, 256, 40960, stream>>>(x, mid, W2, b2, out);
}

// Round 2
// 870.315 us; speedup vs baseline: 1.9400x; 1.9400x over previous
//
#include <hip/hip_runtime.h>

#define NN 100000   // nodes
#define NE 640000   // edges
#define RR 8        // relations
// D = HID = OUT = 128 hard-coded below.

// ---- workspace layout (bytes) ----
// agg/msg : [0,           51200000)   float  N*128
// mid     : [51200000,    153600000)  float  N*256
//   x_bf16 overlays mid[0:25600000)        (used only before k_mlp1 writes mid)
//   Wt_bf16 overlays mid[25600000:...+262144)
// bucket  : [153600000,   156160000)  int    E
// meta    : [156160000,   +128)       int[32]: cnt[0..7], off[8..16], cur[17..24]

typedef unsigned short u16;
typedef u16 u16x4 __attribute__((ext_vector_type(4)));
typedef __bf16 bf16x8 __attribute__((ext_vector_type(8)));
typedef float f32x4 __attribute__((ext_vector_type(4)));

extern __shared__ float lds[];

__device__ inline u16 f2bf(float f) {
  unsigned u = __float_as_uint(f);
  u += 0x7FFF + ((u >> 16) & 1);   // round-to-nearest-even
  return (u16)(u >> 16);
}

// ---------------- dtype prep ----------------
__global__ void k_cvt_x(const float* __restrict__ x, u16* __restrict__ xb) {
  const int i = (blockIdx.x * 256 + threadIdx.x) * 4;   // 12.8M elems, grid covers exactly
  const float4 v = *(const float4*)(x + i);
  u16x4 o;
  o.x = f2bf(v.x); o.y = f2bf(v.y); o.z = f2bf(v.z); o.w = f2bf(v.w);
  *(u16x4*)(xb + i) = o;
}

// Wt[r][o][d] = bf16(W_rel[r][d][o])
__global__ void k_cvt_w(const float* __restrict__ W, u16* __restrict__ Wt) {
  const int idx = blockIdx.x * 256 + threadIdx.x;       // 131072 total
  const int r = idx >> 14, o = (idx >> 7) & 127, d = idx & 127;
  Wt[idx] = f2bf(W[(r << 14) + (d << 7) + o]);
}

// ---------------- bucketing ----------------
__global__ void k_hist(const int* __restrict__ et, int* __restrict__ meta) {
  __shared__ int h[RR];
  const int tid = threadIdx.x;
  if (tid < RR) h[tid] = 0;
  __syncthreads();
  const int e = blockIdx.x * 256 + tid;
  if (e < NE) atomicAdd(&h[et[e]], 1);
  __syncthreads();
  if (tid < RR) atomicAdd(&meta[tid], h[tid]);
}

__global__ void k_scan(int* __restrict__ meta) {
  int s = 0;
  for (int r = 0; r < RR; ++r) { meta[8 + r] = s; meta[17 + r] = s; s += meta[r]; }
  meta[8 + RR] = s;
}

__global__ void k_scatter(const int* __restrict__ et, int* __restrict__ meta,
                          int* __restrict__ bucket) {
  __shared__ int lh[RR], lbase[RR];
  const int tid = threadIdx.x;
  if (tid < RR) lh[tid] = 0;
  __syncthreads();
  const int e = blockIdx.x * 256 + tid;
  int r = 0, lp = 0;
  if (e < NE) { r = et[e]; lp = atomicAdd(&lh[r], 1); }
  __syncthreads();
  if (tid < RR) lbase[tid] = atomicAdd(&meta[17 + tid], lh[tid]);
  __syncthreads();
  if (e < NE) bucket[lbase[r] + lp] = e;
}

// ---------------- edge GEMM (MFMA) + scatter-add ----------------
// Grid: 2048 blocks = 8 relations x 256 slots. Each block keeps the 16
// B-fragments of W_rel[r] (its 64-col half x K=128) in registers and loops
// over 32-edge tiles with stride 256. No LDS, no barriers.
__global__ __launch_bounds__(256, 3) void k_edge(
    const u16* __restrict__ xb, const int* __restrict__ src,
    const int* __restrict__ dst, const u16* __restrict__ Wt,
    const int* __restrict__ meta, const int* __restrict__ bucket,
    float* __restrict__ agg) {
  const int r = blockIdx.x >> 8;
  const int bslot = blockIdx.x & 255;
  const int off0 = meta[8 + r], off1 = meta[9 + r];
  const int ntile = (off1 - off0 + 31) >> 5;

  const int wave = threadIdx.x >> 6;
  const int lane = threadIdx.x & 63;
  const int l16 = lane & 15;
  const int quad = lane >> 4;
  const int rt = wave & 1;            // row-tile within the 32-edge tile
  const int cb = (wave >> 1) << 6;    // column base: 0 or 64

  // preload B fragments: B[k][n], lane holds n=l16, k=quad*8+j
  bf16x8 bfr[4][4];
  const u16* wbase = Wt + ((size_t)r << 14);
#pragma unroll
  for (int c = 0; c < 4; ++c) {
    const u16* wp = wbase + (size_t)(cb + c * 16 + l16) * 128 + quad * 8;
#pragma unroll
    for (int t = 0; t < 4; ++t)
      bfr[c][t] = *(const bf16x8*)(wp + t * 32);
  }

  for (int ti = bslot; ti < ntile; ti += 256) {
    const int base = off0 + (ti << 5);
    const int cnt = min(32, off1 - base);

    // A fragments: A[m][k], lane holds m=l16, k=quad*8+j; gather from global
    const int ar = rt * 16 + l16;
    const int eA = bucket[base + (ar < cnt ? ar : cnt - 1)];
    const u16* xp = xb + ((size_t)src[eA] << 7) + quad * 8;
    bf16x8 afr[4];
#pragma unroll
    for (int t = 0; t < 4; ++t)
      afr[t] = *(const bf16x8*)(xp + t * 32);

    f32x4 acc[4] = {};
#pragma unroll
    for (int c = 0; c < 4; ++c)
#pragma unroll
      for (int t = 0; t < 4; ++t)
        acc[c] = __builtin_amdgcn_mfma_f32_16x16x32_bf16(afr[t], bfr[c][t], acc[c], 0, 0, 0);

    // epilogue: C/D row = quad*4+reg, col = l16
#pragma unroll
    for (int reg = 0; reg < 4; ++reg) {
      const int er = rt * 16 + quad * 4 + reg;
      if (er < cnt) {
        const int e = bucket[base + er];
        float* ap = agg + ((size_t)dst[e] << 7) + cb + l16;
#pragma unroll
        for (int c = 0; c < 4; ++c)
          atomicAdd(ap + c * 16, acc[c][reg]);
      }
    }
  }
}

// ---------------- msg = agg + x @ loop_w + rel_bias (in place over agg) ----
__global__ __launch_bounds__(256) void k_msg(
    const float* __restrict__ x, const float* __restrict__ loop_w,
    const float* __restrict__ rel_bias, float* __restrict__ agg) {
  float* Ws  = lds;         // [64][128]
  float* XgT = lds + 8192;  // [128][32]
  const int tid = threadIdx.x;
  const int tc = tid & 31, tr = tid >> 5;
  const int c0 = 4 * tc, i0 = 4 * tr;
  const int si = tid >> 3, sj = tid & 7;
  const int v0 = blockIdx.x * 32;   // NN divisible by 32

  {
    const float* xr = x + (size_t)(v0 + si) * 128 + sj * 16;
#pragma unroll
    for (int t = 0; t < 16; t += 4) {
      const float4 v = *(const float4*)(xr + t);
      const int k = sj * 16 + t;
      XgT[(k + 0) * 32 + si] = v.x;
      XgT[(k + 1) * 32 + si] = v.y;
      XgT[(k + 2) * 32 + si] = v.z;
      XgT[(k + 3) * 32 + si] = v.w;
    }
  }

  float acc[4][4] = {};
#pragma unroll
  for (int s = 0; s < 2; ++s) {
    for (int idx = tid * 4; idx < 8192; idx += 1024)
      *(float4*)&Ws[idx] = *(const float4*)&loop_w[s * 8192 + idx];
    __syncthreads();
#pragma unroll 4
    for (int kk = 0; kk < 64; ++kk) {
      const float4 av = *(const float4*)&XgT[(s * 64 + kk) * 32 + i0];
      const float4 bv = *(const float4*)&Ws[kk * 128 + c0];
      const float a[4] = {av.x, av.y, av.z, av.w};
      const float b[4] = {bv.x, bv.y, bv.z, bv.w};
#pragma unroll
      for (int ri = 0; ri < 4; ++ri)
#pragma unroll
        for (int ci = 0; ci < 4; ++ci)
          acc[ri][ci] = fmaf(a[ri], b[ci], acc[ri][ci]);
    }
    __syncthreads();
  }

  const float4 bb = *(const float4*)&rel_bias[c0];
#pragma unroll
  for (int ri = 0; ri < 4; ++ri) {
    const size_t row = (size_t)(v0 + i0 + ri) * 128 + c0;
    const float4 g = *(const float4*)&agg[row];
    float4 o;
    o.x = acc[ri][0] + g.x + bb.x;
    o.y = acc[ri][1] + g.y + bb.y;
    o.z = acc[ri][2] + g.z + bb.z;
    o.w = acc[ri][3] + g.w + bb.w;
    *(float4*)&agg[row] = o;
  }
}

// ---------------- mid = tanh([x | msg] @ W1 + b1) ----------------
__global__ __launch_bounds__(256) void k_mlp1(
    const float* __restrict__ x, const float* __restrict__ msg,
    const float* __restrict__ W1, const float* __restrict__ b1,
    float* __restrict__ mid) {
  float* Ws  = lds;         // [32][256] 32KB (K-slice of W1)
  float* ATs = lds + 8192;  // [32][32]   4KB (K-slice of A, transposed)
  const int tid = threadIdx.x;
  const int tc = tid & 31, tr = tid >> 5;
  const int c0 = 4 * tc, i0 = 4 * tr;
  const int si = tid >> 3, sj = tid & 7;
  const int v0 = blockIdx.x * 32;

  float acc[4][8] = {};
  for (int s = 0; s < 8; ++s) {
    {  // stage A slice: global k = s*32 + sj*4 .. +3
      const int kg = s * 32 + sj * 4;
      const float* ap = (kg < 128) ? x + (size_t)(v0 + si) * 128 + kg
                                   : msg + (size_t)(v0 + si) * 128 + (kg - 128);
      const float4 v = *(const float4*)ap;
      ATs[(sj * 4 + 0) * 32 + si] = v.x;
      ATs[(sj * 4 + 1) * 32 + si] = v.y;
      ATs[(sj * 4 + 2) * 32 + si] = v.z;
      ATs[(sj * 4 + 3) * 32 + si] = v.w;
    }
    for (int idx = tid * 4; idx < 8192; idx += 1024)
      *(float4*)&Ws[idx] = *(const float4*)&W1[s * 8192 + idx];
    __syncthreads();
#pragma unroll 4
    for (int kk = 0; kk < 32; ++kk) {
      const float4 av  = *(const float4*)&ATs[kk * 32 + i0];
      const float4 blo = *(const float4*)&Ws[kk * 256 + c0];
      const float4 bhi = *(const float4*)&Ws[kk * 256 + 128 + c0];
      const float a[4]  = {av.x, av.y, av.z, av.w};
      const float bl[4] = {blo.x, blo.y, blo.z, blo.w};
      const float bh[4] = {bhi.x, bhi.y, bhi.z, bhi.w};
#pragma unroll
      for (int ri = 0; ri < 4; ++ri)
#pragma unroll
        for (int ci = 0; ci < 4; ++ci) {
          acc[ri][ci]     = fmaf(a[ri], bl[ci], acc[ri][ci]);
          acc[ri][4 + ci] = fmaf(a[ri], bh[ci], acc[ri][4 + ci]);
        }
    }
    __syncthreads();
  }

  const float4 b1lo = *(const float4*)&b1[c0];
  const float4 b1hi = *(const float4*)&b1[128 + c0];
#pragma unroll
  for (int ri = 0; ri < 4; ++ri) {
    const size_t row = (size_t)(v0 + i0 + ri) * 256;
    float4 o1, o2;
    o1.x = tanhf(acc[ri][0] + b1lo.x);
    o1.y = tanhf(acc[ri][1] + b1lo.y);
    o1.z = tanhf(acc[ri][2] + b1lo.z);
    o1.w = tanhf(acc[ri][3] + b1lo.w);
    o2.x = tanhf(acc[ri][4] + b1hi.x);
    o2.y = tanhf(acc[ri][5] + b1hi.y);
    o2.z = tanhf(acc[ri][6] + b1hi.z);
    o2.w = tanhf(acc[ri][7] + b1hi.w);
    *(float4*)&mid[row + c0] = o1;
    *(float4*)&mid[row + 128 + c0] = o2;
  }
}

// ---------------- out = [x | mid] @ W2 + b2 ----------------
__global__ __launch_bounds__(256) void k_mlp2(
    const float* __restrict__ x, const float* __restrict__ mid,
    const float* __restrict__ W2, const float* __restrict__ b2,
    float* __restrict__ out) {
  float* Ws  = lds;         // [64][128] 32KB (K-slice of W2)
  float* ATs = lds + 8192;  // [64][32]   8KB
  const int tid = threadIdx.x;
  const int tc = tid & 31, tr = tid >> 5;
  const int c0 = 4 * tc, i0 = 4 * tr;
  const int si = tid >> 3, sj = tid & 7;
  const int v0 = blockIdx.x * 32;

  float acc[4][4] = {};
  for (int s = 0; s < 6; ++s) {
    {  // stage A slice: global k = s*64 + sj*8 .. +7
      const int kg = s * 64 + sj * 8;
      const float* ap = (kg < 128) ? x + (size_t)(v0 + si) * 128 + kg
                                   : mid + (size_t)(v0 + si) * 256 + (kg - 128);
#pragma unroll
      for (int t = 0; t < 8; t += 4) {
        const float4 v = *(const float4*)(ap + t);
        const int kl = sj * 8 + t;
        ATs[(kl + 0) * 32 + si] = v.x;
        ATs[(kl + 1) * 32 + si] = v.y;
        ATs[(kl + 2) * 32 + si] = v.z;
        ATs[(kl + 3) * 32 + si] = v.w;
      }
    }
    for (int idx = tid * 4; idx < 8192; idx += 1024)
      *(float4*)&Ws[idx] = *(const float4*)&W2[s * 8192 + idx];
    __syncthreads();
#pragma unroll 4
    for (int kk = 0; kk < 64; ++kk) {
      const float4 av = *(const float4*)&ATs[kk * 32 + i0];
      const float4 bv = *(const float4*)&Ws[kk * 128 + c0];
      const float a[4] = {av.x, av.y, av.z, av.w};
      const float b[4] = {bv.x, bv.y, bv.z, bv.w};
#pragma unroll
      for (int ri = 0; ri < 4; ++ri)
#pragma unroll
        for (int ci = 0; ci < 4; ++ci)
          acc[ri][ci] = fmaf(a[ri], b[ci], acc[ri][ci]);
    }
    __syncthreads();
  }

  const float4 bb = *(const float4*)&b2[c0];
#pragma unroll
  for (int ri = 0; ri < 4; ++ri) {
    const size_t row = (size_t)(v0 + i0 + ri) * 128 + c0;
    float4 o;
    o.x = acc[ri][0] + bb.x;
    o.y = acc[ri][1] + bb.y;
    o.z = acc[ri][2] + bb.z;
    o.w = acc[ri][3] + bb.w;
    *(float4*)&out[row] = o;
  }
}

extern "C" void kernel_launch(void* const* d_in, const int* in_sizes, int n_in,
                              void* d_out, int out_size, void* d_ws, size_t ws_size,
                              hipStream_t stream) {
  (void)in_sizes; (void)n_in; (void)out_size; (void)ws_size;
  const float* x        = (const float*)d_in[0];
  const int*   src      = (const int*)d_in[1];
  const int*   dst      = (const int*)d_in[2];
  const int*   et       = (const int*)d_in[3];
  const float* W_rel    = (const float*)d_in[4];
  const float* loop_w   = (const float*)d_in[5];
  const float* rel_bias = (const float*)d_in[6];
  const float* W1       = (const float*)d_in[7];
  const float* b1       = (const float*)d_in[8];
  const float* W2       = (const float*)d_in[9];
  const float* b2       = (const float*)d_in[10];
  float* out = (float*)d_out;

  char* ws = (char*)d_ws;
  float* agg    = (float*)ws;                   // N*128 floats
  float* mid    = (float*)(ws + 51200000);      // N*256 floats (used by mlp1/2)
  u16*   xb     = (u16*)(ws + 51200000);        // x in bf16 (overlays mid; dead before mlp1)
  u16*   Wt     = (u16*)(ws + 76800000);        // W_rel bf16, transposed [r][o][d]
  int*   bucket = (int*)(ws + 153600000);       // E ints
  int*   meta   = (int*)(ws + 156160000);       // 32 ints

  hipMemsetAsync(agg, 0, (size_t)NN * 128 * sizeof(float), stream);
  hipMemsetAsync(meta, 0, 128, stream);

  k_cvt_x<<<(NN * 128) / 1024, 256, 0, stream>>>(x, xb);
  k_cvt_w<<<(RR * 128 * 128) / 256, 256, 0, stream>>>(W_rel, Wt);
  k_hist<<<(NE + 255) / 256, 256, 0, stream>>>(et, meta);
  k_scan<<<1, 1, 0, stream>>>(meta);
  k_scatter<<<(NE + 255) / 256, 256, 0, stream>>>(et, meta, bucket);
  k_edge<<<RR * 256, 256, 0, stream>>>(xb, src, dst, Wt, meta, bucket, agg);
  k_msg<<<NN / 32, 256, 49152, stream>>>(x, loop_w, rel_bias, agg);
  k_mlp1<<<NN / 32, 256, 36864, stream>>>(x, agg, W1, b1, mid);
  k_mlp2<<<NN / 32, 256, 40960, stream>>>(x, mid, W2, b2, out);
}

// Round 3
// 638.735 us; speedup vs baseline: 2.6434x; 1.3626x over previous
//
#include <hip/hip_runtime.h>

#define NN 100000   // nodes
#define NE 640000   // edges
#define RR 8        // relations
#define NBIN 800000 // NN*8 csr bins
// D = HID = OUT = 128 hard-coded below.

typedef unsigned short u16;
typedef u16 u16x4 __attribute__((ext_vector_type(4)));
typedef u16 u16x8 __attribute__((ext_vector_type(8)));
typedef __bf16 bf16x8 __attribute__((ext_vector_type(8)));
typedef float f32x4 __attribute__((ext_vector_type(4)));

// ---- workspace layout (bytes) ----
#define OFF_MSG     0u          // fp32 N*128            = 51,200,000
#define OFF_MIDB    51200000u   // bf16 N*256            = 51,200,000
#define OFF_XB      102400000u  // bf16 N*128            = 25,600,000
#define OFF_WT      128000000u  // bf16 [9][128o][128d]  = 294,912 (8 rels + loop_w)
#define OFF_W1T     128296960u  // bf16 [256o][256i]     = 131,072
#define OFF_W2T     128428032u  // bf16 [128o][384i]     = 98,304
#define OFF_BUCKET  128527360u  // int  E (src values)   = 2,560,000
#define OFF_CSROFF  131088384u  // int  NBIN+1           = 3,200,004
#define OFF_CUR     134289408u  // int  NBIN             = 3,200,000
#define OFF_PSUM    137490432u  // int  1024

__device__ inline u16 f2bf(float f) {
  unsigned u = __float_as_uint(f);
  u += 0x7FFF + ((u >> 16) & 1);   // round-to-nearest-even
  return (u16)(u >> 16);
}
__device__ inline float bf2f(u16 h) { return __uint_as_float(((unsigned)h) << 16); }

// ---------------- dtype prep ----------------
__global__ void k_cvt_x(const float* __restrict__ x, u16* __restrict__ xb) {
  const int i = (blockIdx.x * 256 + threadIdx.x) * 4;
  const float4 v = *(const float4*)(x + i);
  u16x4 o;
  o.x = f2bf(v.x); o.y = f2bf(v.y); o.z = f2bf(v.z); o.w = f2bf(v.w);
  *(u16x4*)(xb + i) = o;
}

// Wt[r][o][d]: r<8 from W_rel, r==8 from loop_w
__global__ void k_cvt_wrel(const float* __restrict__ W, const float* __restrict__ Lw,
                           u16* __restrict__ Wt) {
  const int idx = blockIdx.x * 256 + threadIdx.x;      // 9*16384 total
  const int r = idx >> 14, o = (idx >> 7) & 127, d = idx & 127;
  Wt[idx] = f2bf(r < 8 ? W[(r << 14) + (d << 7) + o] : Lw[(d << 7) + o]);
}

__global__ void k_cvt_w1(const float* __restrict__ W1, u16* __restrict__ W1t) {
  const int idx = blockIdx.x * 256 + threadIdx.x;      // 65536
  const int o = idx >> 8, i = idx & 255;
  W1t[idx] = f2bf(W1[i * 256 + o]);
}

__global__ void k_cvt_w2(const float* __restrict__ W2, u16* __restrict__ W2t) {
  const int idx = blockIdx.x * 256 + threadIdx.x;      // 49152
  const int o = idx / 384, i = idx % 384;
  W2t[idx] = f2bf(W2[i * 128 + o]);
}

// ---------------- CSR build: key = dst*8 + etype ----------------
__global__ void k_hist(const int* __restrict__ dst, const int* __restrict__ et,
                       int* __restrict__ cnt) {
  const int e = blockIdx.x * 256 + threadIdx.x;
  if (e < NE) atomicAdd(&cnt[dst[e] * 8 + et[e]], 1);
}

__global__ void k_scanA(const int* __restrict__ cnt, int* __restrict__ psum) {
  __shared__ int sc[256];
  const int tid = threadIdx.x, base = blockIdx.x * 1024 + tid * 4;
  int s = 0;
#pragma unroll
  for (int t = 0; t < 4; ++t) { const int i = base + t; if (i < NBIN) s += cnt[i]; }
  sc[tid] = s; __syncthreads();
  for (int d = 128; d > 0; d >>= 1) {
    if (tid < d) sc[tid] += sc[tid + d];
    __syncthreads();
  }
  if (tid == 0) psum[blockIdx.x] = sc[0];
}

__global__ void k_scanB(int* __restrict__ psum) {
  __shared__ int sc[1024];
  const int tid = threadIdx.x;
  const int v = (tid < 782) ? psum[tid] : 0;
  sc[tid] = v; __syncthreads();
  for (int d = 1; d < 1024; d <<= 1) {
    const int t = (tid >= d) ? sc[tid - d] : 0;
    __syncthreads();
    sc[tid] += t;
    __syncthreads();
  }
  if (tid < 782) psum[tid] = sc[tid] - v;   // exclusive
}

__global__ void k_scanC(int* __restrict__ cnt /*=cur*/, const int* __restrict__ psum,
                        int* __restrict__ off) {
  __shared__ int sc[256];
  const int tid = threadIdx.x, base = blockIdx.x * 1024 + tid * 4;
  int c[4], s = 0;
#pragma unroll
  for (int t = 0; t < 4; ++t) {
    const int i = base + t;
    c[t] = (i < NBIN) ? cnt[i] : 0;
    s += c[t];
  }
  sc[tid] = s; __syncthreads();
  for (int d = 1; d < 256; d <<= 1) {
    const int t = (tid >= d) ? sc[tid - d] : 0;
    __syncthreads();
    sc[tid] += t;
    __syncthreads();
  }
  int run = psum[blockIdx.x] + sc[tid] - s;   // exclusive thread base
#pragma unroll
  for (int t = 0; t < 4; ++t) {
    const int i = base + t;
    if (i < NBIN) { off[i] = run; cnt[i] = run; run += c[t]; }
  }
  if (blockIdx.x == 0 && tid == 0) off[NBIN] = NE;
}

__global__ void k_scatter(const int* __restrict__ src, const int* __restrict__ dst,
                          const int* __restrict__ et, int* __restrict__ cur,
                          int* __restrict__ bucket) {
  const int e = blockIdx.x * 256 + threadIdx.x;
  if (e < NE) {
    const int pos = atomicAdd(&cur[dst[e] * 8 + et[e]], 1);
    bucket[pos] = src[e];   // store src directly; dst/rel implied by segment
  }
}

// ---------------- fused edge-aggregate + transform + self-loop + bias ----
// agg[v] = sum_r (sum_{e in (v,r)} x[src[e]]) @ W_r ; + x[v]@loop_w + rel_bias
// One block per 32 dst nodes. 9 passes (8 rels + self). Zero atomics.
#define ATS 136   // A-tile row stride in u16: 272 B = 68 words, 68%32=4 -> 2-way-free
__global__ __launch_bounds__(256) void k_edge_msg(
    const u16* __restrict__ xb, const u16* __restrict__ Wt,
    const int* __restrict__ csroff, const int* __restrict__ bucket,
    const float* __restrict__ rel_bias, float* __restrict__ msg) {
  __shared__ u16 At[32 * ATS];
  __shared__ int soff[257];
  const int tid = threadIdx.x;
  const int v0 = blockIdx.x * 32;

  soff[tid] = csroff[v0 * 8 + tid];
  if (tid == 0) soff[256] = csroff[v0 * 8 + 256];

  const int wave = tid >> 6, lane = tid & 63;
  const int l16 = lane & 15, quad = lane >> 4;
  const int rt = wave & 1, cb = (wave >> 1) << 6;
  const int si = tid >> 3, sj = tid & 7;
  __syncthreads();

  f32x4 acc[4] = {};

  for (int r = 0; r < 9; ++r) {
    // ---- build summed-A tile (fp32 accumulate in regs) ----
    float a[16] = {};
    int pbeg, pend;
    if (r < 8) { pbeg = soff[si * 8 + r]; pend = soff[si * 8 + r + 1]; }
    else       { pbeg = 0; pend = 1; }
    for (int p = pbeg; p < pend; ++p) {
      const int s = (r < 8) ? bucket[p] : (v0 + si);
      const u16* xp = xb + ((size_t)s << 7) + sj * 16;
      const u16x8 h0 = *(const u16x8*)(xp);
      const u16x8 h1 = *(const u16x8*)(xp + 8);
#pragma unroll
      for (int t = 0; t < 8; ++t) { a[t] += bf2f(h0[t]); a[8 + t] += bf2f(h1[t]); }
    }
    u16x8 o0, o1;
#pragma unroll
    for (int t = 0; t < 8; ++t) { o0[t] = f2bf(a[t]); o1[t] = f2bf(a[8 + t]); }
    *(u16x8*)&At[si * ATS + sj * 16]     = o0;
    *(u16x8*)&At[si * ATS + sj * 16 + 8] = o1;
    __syncthreads();

    // ---- MFMA: A-tile @ W_r, accumulate across passes ----
    bf16x8 afr[4];
#pragma unroll
    for (int t = 0; t < 4; ++t)
      afr[t] = *(const bf16x8*)&At[(rt * 16 + l16) * ATS + quad * 8 + t * 32];
    const u16* wb = Wt + (r << 14);
#pragma unroll
    for (int c = 0; c < 4; ++c) {
      const u16* wp = wb + (size_t)(cb + c * 16 + l16) * 128 + quad * 8;
#pragma unroll
      for (int t = 0; t < 4; ++t)
        acc[c] = __builtin_amdgcn_mfma_f32_16x16x32_bf16(afr[t], *(const bf16x8*)(wp + t * 32), acc[c], 0, 0, 0);
    }
    __syncthreads();
  }

  // ---- epilogue: + rel_bias, single fp32 write ----
#pragma unroll
  for (int c = 0; c < 4; ++c) {
    const int col = cb + c * 16 + l16;
    const float bias = rel_bias[col];
#pragma unroll
    for (int reg = 0; reg < 4; ++reg) {
      const int row = v0 + rt * 16 + quad * 4 + reg;
      msg[(size_t)row * 128 + col] = acc[c][reg] + bias;
    }
  }
}

// ---------------- mid = tanh([x | msg] @ W1 + b1), bf16 MFMA -------------
#define A1S 264   // 256+8 u16: 132 words, %32=4
__global__ __launch_bounds__(256) void k_mlp1(
    const u16* __restrict__ xb, const float* __restrict__ msg,
    const u16* __restrict__ W1t, const float* __restrict__ b1,
    u16* __restrict__ midb) {
  __shared__ u16 At[32 * A1S];
  const int tid = threadIdx.x;
  const int v0 = blockIdx.x * 32;
  const int si = tid >> 3, sj = tid & 7;

  { // stage x -> cols 0..127
    const u16* xp = xb + ((size_t)(v0 + si) << 7) + sj * 16;
    *(u16x8*)&At[si * A1S + sj * 16]     = *(const u16x8*)(xp);
    *(u16x8*)&At[si * A1S + sj * 16 + 8] = *(const u16x8*)(xp + 8);
  }
  { // stage msg (fp32) -> cols 128..255
    const float* mp = msg + (size_t)(v0 + si) * 128 + sj * 16;
    u16x8 o0, o1;
#pragma unroll
    for (int t = 0; t < 8; ++t) { o0[t] = f2bf(mp[t]); o1[t] = f2bf(mp[8 + t]); }
    *(u16x8*)&At[si * A1S + 128 + sj * 16]     = o0;
    *(u16x8*)&At[si * A1S + 128 + sj * 16 + 8] = o1;
  }
  __syncthreads();

  const int wave = tid >> 6, lane = tid & 63;
  const int l16 = lane & 15, quad = lane >> 4;
  const int rt = wave & 1, ch = (wave >> 1) << 7;

  f32x4 acc[8] = {};
  for (int kt = 0; kt < 8; ++kt) {
    const bf16x8 af = *(const bf16x8*)&At[(rt * 16 + l16) * A1S + kt * 32 + quad * 8];
#pragma unroll
    for (int ct = 0; ct < 8; ++ct) {
      const u16* wp = W1t + (size_t)(ch + ct * 16 + l16) * 256 + kt * 32 + quad * 8;
      acc[ct] = __builtin_amdgcn_mfma_f32_16x16x32_bf16(af, *(const bf16x8*)(wp), acc[ct], 0, 0, 0);
    }
  }

#pragma unroll
  for (int ct = 0; ct < 8; ++ct) {
    const int col = ch + ct * 16 + l16;
    const float bias = b1[col];
#pragma unroll
    for (int reg = 0; reg < 4; ++reg) {
      const int row = v0 + rt * 16 + quad * 4 + reg;
      midb[(size_t)row * 256 + col] = f2bf(tanhf(acc[ct][reg] + bias));
    }
  }
}

// ---------------- out = [x | mid] @ W2 + b2, bf16 MFMA -------------------
#define A2S 392   // 384+8 u16: 196 words, %32=4
__global__ __launch_bounds__(256) void k_mlp2(
    const u16* __restrict__ xb, const u16* __restrict__ midb,
    const u16* __restrict__ W2t, const float* __restrict__ b2,
    float* __restrict__ out) {
  __shared__ u16 At[32 * A2S];
  const int tid = threadIdx.x;
  const int v0 = blockIdx.x * 32;
  const int si = tid >> 3, sj = tid & 7;

  { // stage x -> cols 0..127
    const u16* xp = xb + ((size_t)(v0 + si) << 7) + sj * 16;
    *(u16x8*)&At[si * A2S + sj * 16]     = *(const u16x8*)(xp);
    *(u16x8*)&At[si * A2S + sj * 16 + 8] = *(const u16x8*)(xp + 8);
  }
  { // stage mid -> cols 128..383 (32 u16 per thread)
    const u16* mp = midb + ((size_t)(v0 + si) << 8) + sj * 32;
#pragma unroll
    for (int t = 0; t < 4; ++t)
      *(u16x8*)&At[si * A2S + 128 + sj * 32 + t * 8] = *(const u16x8*)(mp + t * 8);
  }
  __syncthreads();

  const int wave = tid >> 6, lane = tid & 63;
  const int l16 = lane & 15, quad = lane >> 4;
  const int rt = wave & 1, cb = (wave >> 1) << 6;

  f32x4 acc[4] = {};
  for (int kt = 0; kt < 12; ++kt) {
    const bf16x8 af = *(const bf16x8*)&At[(rt * 16 + l16) * A2S + kt * 32 + quad * 8];
#pragma unroll
    for (int ct = 0; ct < 4; ++ct) {
      const u16* wp = W2t + (size_t)(cb + ct * 16 + l16) * 384 + kt * 32 + quad * 8;
      acc[ct] = __builtin_amdgcn_mfma_f32_16x16x32_bf16(af, *(const bf16x8*)(wp), acc[ct], 0, 0, 0);
    }
  }

#pragma unroll
  for (int ct = 0; ct < 4; ++ct) {
    const int col = cb + ct * 16 + l16;
    const float bias = b2[col];
#pragma unroll
    for (int reg = 0; reg < 4; ++reg) {
      const int row = v0 + rt * 16 + quad * 4 + reg;
      out[(size_t)row * 128 + col] = acc[ct][reg] + bias;
    }
  }
}

extern "C" void kernel_launch(void* const* d_in, const int* in_sizes, int n_in,
                              void* d_out, int out_size, void* d_ws, size_t ws_size,
                              hipStream_t stream) {
  (void)in_sizes; (void)n_in; (void)out_size; (void)ws_size;
  const float* x        = (const float*)d_in[0];
  const int*   src      = (const int*)d_in[1];
  const int*   dst      = (const int*)d_in[2];
  const int*   et       = (const int*)d_in[3];
  const float* W_rel    = (const float*)d_in[4];
  const float* loop_w   = (const float*)d_in[5];
  const float* rel_bias = (const float*)d_in[6];
  const float* W1       = (const float*)d_in[7];
  const float* b1       = (const float*)d_in[8];
  const float* W2       = (const float*)d_in[9];
  const float* b2       = (const float*)d_in[10];
  float* out = (float*)d_out;

  char* ws = (char*)d_ws;
  float* msg    = (float*)(ws + OFF_MSG);
  u16*   midb   = (u16*)(ws + OFF_MIDB);
  u16*   xb     = (u16*)(ws + OFF_XB);
  u16*   Wt     = (u16*)(ws + OFF_WT);
  u16*   W1t    = (u16*)(ws + OFF_W1T);
  u16*   W2t    = (u16*)(ws + OFF_W2T);
  int*   bucket = (int*)(ws + OFF_BUCKET);
  int*   csroff = (int*)(ws + OFF_CSROFF);
  int*   cur    = (int*)(ws + OFF_CUR);
  int*   psum   = (int*)(ws + OFF_PSUM);

  hipMemsetAsync(cur, 0, (size_t)NBIN * 4, stream);

  k_cvt_x   <<<(NN * 128) / 1024, 256, 0, stream>>>(x, xb);
  k_cvt_wrel<<<(9 * 16384) / 256, 256, 0, stream>>>(W_rel, loop_w, Wt);
  k_cvt_w1  <<<(256 * 256) / 256, 256, 0, stream>>>(W1, W1t);
  k_cvt_w2  <<<(128 * 384) / 256, 256, 0, stream>>>(W2, W2t);

  k_hist    <<<(NE + 255) / 256, 256, 0, stream>>>(dst, et, cur);
  k_scanA   <<<782, 256, 0, stream>>>(cur, psum);
  k_scanB   <<<1, 1024, 0, stream>>>(psum);
  k_scanC   <<<782, 256, 0, stream>>>(cur, psum, csroff);
  k_scatter <<<(NE + 255) / 256, 256, 0, stream>>>(src, dst, et, cur, bucket);

  k_edge_msg<<<NN / 32, 256, 0, stream>>>(xb, Wt, csroff, bucket, rel_bias, msg);
  k_mlp1    <<<NN / 32, 256, 0, stream>>>(xb, msg, W1t, b1, midb);
  k_mlp2    <<<NN / 32, 256, 0, stream>>>(xb, midb, W2t, b2, out);
}